// Round 1
// baseline (2082.282 us; speedup 1.0000x reference)
//
// MultiFactorAttention MI355X pipeline — Round 3 (dtype-adaptive + small ws)
//
// Kills both remaining failure hypotheses:
//  - runtime dtype detection (bf16 vs fp32 input buffers), uniform flag in ws,
//    dual-path loads everywhere; output written in the detected dtype.
//  - workspace cut to 49.4 MB (<64 MiB) via 4 passes of 16 batches for K/V.
//
//  k_detect   : flag = is_bf16(y_hat bits); biases -> float ws arrays
//  k_wtrans   : WqT/WsT/WkT/WvT (bf16, transposed for B-operand)
//  per pass p (16 batches): k_kvgemm (K[s][d], VT[d][s]) ; k_fused
//  k_softmax_final ; k_output

#include <hip/hip_runtime.h>
#include <hip/hip_bf16.h>

typedef __bf16 bf16_t;
typedef bf16_t bf16x8 __attribute__((ext_vector_type(8)));
typedef bf16_t bf16x4 __attribute__((ext_vector_type(4)));
typedef float  floatx4 __attribute__((ext_vector_type(4)));

#define MFMA16(a,b,c) __builtin_amdgcn_mfma_f32_16x16x32_bf16((a),(b),(c),0,0,0)

constexpr int T_ = 1024, TF_ = 512, S_ = 1536, F_ = 32;
constexpr int BPP = 16;                       // batches per pass
constexpr float INV_SCALE = 0.04419417382415922f;  // 1/sqrt(512)

// ---- dual-path load helpers (isbf is wave-uniform) ----
__device__ __forceinline__ bf16x8 load8(const void* p, size_t idx, int isbf) {
    if (isbf) return *(const bf16x8*)((const bf16_t*)p + idx);
    const floatx4* f = (const floatx4*)((const float*)p + idx);
    floatx4 a = f[0], b = f[1];
    bf16x8 r;
    r[0]=(bf16_t)a[0]; r[1]=(bf16_t)a[1]; r[2]=(bf16_t)a[2]; r[3]=(bf16_t)a[3];
    r[4]=(bf16_t)b[0]; r[5]=(bf16_t)b[1]; r[6]=(bf16_t)b[2]; r[7]=(bf16_t)b[3];
    return r;
}
__device__ __forceinline__ float loadf(const void* p, size_t idx, int isbf) {
    return isbf ? (float)((const bf16_t*)p)[idx] : ((const float*)p)[idx];
}

// ---------------- dtype detect + bias normalize ----------------
__global__ __launch_bounds__(256) void k_detect(
    const void* __restrict__ y, int* __restrict__ flag,
    const void* __restrict__ bq, const void* __restrict__ bk,
    const void* __restrict__ bv, const void* __restrict__ bs,
    float* __restrict__ bqf, float* __restrict__ bkf,
    float* __restrict__ bvf, float* __restrict__ bsf)
{
    __shared__ int cnt[4];
    const unsigned* w = (const unsigned*)y;
    unsigned x = w[threadIdx.x];
    unsigned e = (x >> 7) & 0xFFu;            // bf16-exponent field of LOW half
    bool hit = (e >= 100u && e <= 141u);      // plausible N(0,1) bf16 exponent
    unsigned long long m = __ballot(hit);
    if ((threadIdx.x & 63) == 0) cnt[threadIdx.x >> 6] = __popcll(m);
    __syncthreads();
    int isbf = (cnt[0] + cnt[1] + cnt[2] + cnt[3]) >= 128;
    if (threadIdx.x == 0) *flag = isbf;
    for (int i = threadIdx.x; i < 512; i += 256) {
        bqf[i] = loadf(bq, i, isbf);
        bkf[i] = loadf(bk, i, isbf);
        bvf[i] = loadf(bv, i, isbf);
        bsf[i] = loadf(bs, i, isbf);
    }
}

// ---------------- weight transposes (output always bf16) ----------------
__global__ __launch_bounds__(256) void k_wtrans(
    const void* __restrict__ Wq, const void* __restrict__ Ws,
    const void* __restrict__ Wk, const void* __restrict__ Wv,
    bf16_t* __restrict__ WqT, bf16_t* __restrict__ WsT,
    bf16_t* __restrict__ WkT, bf16_t* __restrict__ WvT,
    const int* __restrict__ flag)
{
    int isbf = *flag;
    int idx = blockIdx.x * 256 + threadIdx.x;
    if (idx < 262144) {                       // 512x512
        int k = idx >> 9, n = idx & 511;
        WqT[n * 512 + k] = (bf16_t)loadf(Wq, idx, isbf);
        WsT[n * 512 + k] = (bf16_t)loadf(Ws, idx, isbf);
    }
    if (idx < 16384) {                        // 32x512
        int f = idx >> 9, n = idx & 511;
        WkT[n * 32 + f] = (bf16_t)loadf(Wk, idx, isbf);
        WvT[n * 32 + f] = (bf16_t)loadf(Wv, idx, isbf);
    }
}

// ---------------- K,V GEMMs for one 16-batch pass ----------------
__global__ __launch_bounds__(256) void k_kvgemm(
    const void* __restrict__ hist, const void* __restrict__ fore,
    const bf16_t* __restrict__ WkT, const bf16_t* __restrict__ WvT,
    const float* __restrict__ bkf, const float* __restrict__ bvf,
    bf16_t* __restrict__ K, bf16_t* __restrict__ VT,
    const int* __restrict__ flag, int b0)
{
    int isbf = *flag;
    int wave = threadIdx.x >> 6, lane = threadIdx.x & 63;
    int l15 = lane & 15, quad = lane >> 4;
    int row0 = blockIdx.x * 16;               // local row in [0, BPP*S)
    int lb = row0 / S_;
    int s0 = row0 - lb * S_;
    int bg = b0 + lb;
    int n0 = wave * 128;
    int s = s0 + l15;
    const void* src; size_t eidx;
    if (s < T_) { src = hist; eidx = ((size_t)bg * T_ + s) * F_ + quad * 8; }
    else        { src = fore; eidx = ((size_t)bg * TF_ + (s - T_)) * F_ + quad * 8; }
    bf16x8 a = load8(src, eidx, isbf);
    floatx4 ak[8] = {}, av[8] = {};
#pragma unroll
    for (int nt = 0; nt < 8; ++nt) {
        bf16x8 bk_ = *(const bf16x8*)(WkT + (size_t)(n0 + nt * 16 + l15) * 32 + quad * 8);
        bf16x8 bv_ = *(const bf16x8*)(WvT + (size_t)(n0 + nt * 16 + l15) * 32 + quad * 8);
        ak[nt] = MFMA16(a, bk_, ak[nt]);
        av[nt] = MFMA16(a, bv_, av[nt]);
    }
#pragma unroll
    for (int nt = 0; nt < 8; ++nt) {
        int col = n0 + nt * 16 + l15;
        float bkv = bkf[col], bvv = bvf[col];
        bf16x4 vpack;
#pragma unroll
        for (int reg = 0; reg < 4; ++reg) {
            int row = row0 + quad * 4 + reg;
            K[(size_t)row * 512 + col] = (bf16_t)(ak[nt][reg] + bkv);
            vpack[reg] = (bf16_t)(av[nt][reg] + bvv);
        }
        int sl = s0 + quad * 4;
        *(bf16x4*)(VT + ((size_t)lb * 512 + col) * S_ + sl) = vpack;
    }
}

// ---------------- fused Q-GEMM + flash + epilogue GEMM/logits ----------------
__global__ __launch_bounds__(256) void k_fused(
    const void* __restrict__ Y, const bf16_t* __restrict__ WqT,
    const float* __restrict__ bqf, const bf16_t* __restrict__ Kg,
    const bf16_t* __restrict__ VT, const bf16_t* __restrict__ WsT,
    const float* __restrict__ bsf, float* __restrict__ logits,
    const int* __restrict__ flag, int b0)
{
    __shared__ union {
        float sc[4][32][68];        // 34816 B, flash score staging
        bf16_t tile[32][520];       // 33280 B, Q/corr tile staging (C->A layout)
    } u;
    __shared__ float l_lds[32];
    __shared__ float part[4][32];

    const int isbf = *flag;
    const int wave = threadIdx.x >> 6, lane = threadIdx.x & 63;
    const int l15 = lane & 15, quad = lane >> 4;
    const int lb = blockIdx.x >> 5;
    const int bg = b0 + lb;
    const int t0 = (blockIdx.x & 31) * 32;
    const int n0 = wave * 128;                 // this wave's 128-col (d) slice

    if (threadIdx.x < 32) l_lds[threadIdx.x] = 0.f;

    // ---- Phase A: Q tile = Y[t0..t0+32) @ Wq + bq ----
    {
        floatx4 acc[2][8] = {};
        const size_t abase0 = ((size_t)bg * T_ + t0 + l15) * 512 + quad * 8;
        const size_t abase1 = abase0 + 16 * 512;
        const bf16_t* bbase = WqT + (size_t)(n0 + l15) * 512 + quad * 8;
        for (int ks = 0; ks < 16; ++ks) {
            bf16x8 a0 = load8(Y, abase0 + ks * 32, isbf);
            bf16x8 a1 = load8(Y, abase1 + ks * 32, isbf);
#pragma unroll
            for (int nt = 0; nt < 8; ++nt) {
                bf16x8 bb = *(const bf16x8*)(bbase + (size_t)nt * 16 * 512 + ks * 32);
                acc[0][nt] = MFMA16(a0, bb, acc[0][nt]);
                acc[1][nt] = MFMA16(a1, bb, acc[1][nt]);
            }
        }
#pragma unroll
        for (int nt = 0; nt < 8; ++nt) {
            int col = n0 + nt * 16 + l15;
            float bqv = bqf[col];
#pragma unroll
            for (int mt = 0; mt < 2; ++mt)
#pragma unroll
                for (int reg = 0; reg < 4; ++reg)
                    u.tile[mt * 16 + quad * 4 + reg][col] = (bf16_t)(acc[mt][nt][reg] + bqv);
        }
    }
    __syncthreads();
    bf16x8 qf[2][4];                            // A-frags, this wave's d-slice
#pragma unroll
    for (int mt = 0; mt < 2; ++mt)
#pragma unroll
        for (int ks = 0; ks < 4; ++ks)
            qf[mt][ks] = *(const bf16x8*)&u.tile[mt * 16 + l15][n0 + ks * 32 + quad * 8];
    __syncthreads();                            // tile reads done; sc may overwrite

    // ---- Phase B: streaming attention, 24 chunks of 64 s ----
    floatx4 o[2][8] = {};
    const bf16_t* Kb = Kg + (size_t)lb * S_ * 512;
    const bf16_t* Vb = VT + (size_t)lb * 512 * S_;
    for (int c = 0; c < 24; ++c) {
        int sBase = c * 64;
        floatx4 scp[2][4] = {};                 // partial scores, this wave's d-slice
#pragma unroll
        for (int nt = 0; nt < 4; ++nt)
#pragma unroll
            for (int ks = 0; ks < 4; ++ks) {
                bf16x8 kf = *(const bf16x8*)(Kb + (size_t)(sBase + nt * 16 + l15) * 512
                                               + n0 + ks * 32 + quad * 8);
                scp[0][nt] = MFMA16(qf[0][ks], kf, scp[0][nt]);
                scp[1][nt] = MFMA16(qf[1][ks], kf, scp[1][nt]);
            }
        __syncthreads();                        // prior chunk's sc consumers done
#pragma unroll
        for (int mt = 0; mt < 2; ++mt)
#pragma unroll
            for (int nt = 0; nt < 4; ++nt)
#pragma unroll
                for (int reg = 0; reg < 4; ++reg)
                    u.sc[wave][mt * 16 + quad * 4 + reg][nt * 16 + l15] = scp[mt][nt][reg];
        __syncthreads();
        // rebuild P in A-operand layout (all waves build identical frags)
        bf16x8 pf[2][2];
        float rs[2];
#pragma unroll
        for (int mt = 0; mt < 2; ++mt) {
            float rowsum = 0.f;
#pragma unroll
            for (int kk = 0; kk < 2; ++kk) {
                int row = mt * 16 + l15, colb = kk * 32 + quad * 8;
                float v[8];
#pragma unroll
                for (int j = 0; j < 8; ++j)
                    v[j] = u.sc[0][row][colb + j] + u.sc[1][row][colb + j]
                         + u.sc[2][row][colb + j] + u.sc[3][row][colb + j];
#pragma unroll
                for (int j = 0; j < 8; ++j) {
                    v[j] = __expf(v[j] * INV_SCALE);
                    rowsum += v[j];
                    pf[mt][kk][j] = (bf16_t)v[j];
                }
            }
            rs[mt] = rowsum;
        }
        if (wave == 0) {
#pragma unroll
            for (int mt = 0; mt < 2; ++mt) {
                float r = rs[mt];
                r += __shfl_xor(r, 16);
                r += __shfl_xor(r, 32);
                if (quad == 0) l_lds[mt * 16 + l15] += r;
            }
        }
#pragma unroll
        for (int nt = 0; nt < 8; ++nt)
#pragma unroll
            for (int kk = 0; kk < 2; ++kk) {
                bf16x8 vf = *(const bf16x8*)(Vb + (size_t)(n0 + nt * 16 + l15) * S_
                                               + sBase + kk * 32 + quad * 8);
                o[0][nt] = MFMA16(pf[0][kk], vf, o[0][nt]);
                o[1][nt] = MFMA16(pf[1][kk], vf, o[1][nt]);
            }
    }
    __syncthreads();                            // l_lds final; sc reads all done

    // ---- Phase C: corr tile -> LDS, corr@Ws + bs, dot y_hat -> logits ----
#pragma unroll
    for (int mt = 0; mt < 2; ++mt)
#pragma unroll
        for (int reg = 0; reg < 4; ++reg) {
            float li = 1.f / l_lds[mt * 16 + quad * 4 + reg];
#pragma unroll
            for (int nt = 0; nt < 8; ++nt)
                u.tile[mt * 16 + quad * 4 + reg][n0 + nt * 16 + l15] =
                    (bf16_t)(o[mt][nt][reg] * li);
        }
    __syncthreads();
    {
        floatx4 acc[2][8] = {};
        const bf16_t* bbase = WsT + (size_t)(n0 + l15) * 512 + quad * 8;
        for (int ks = 0; ks < 16; ++ks) {
            bf16x8 a0 = *(const bf16x8*)&u.tile[l15][ks * 32 + quad * 8];
            bf16x8 a1 = *(const bf16x8*)&u.tile[16 + l15][ks * 32 + quad * 8];
#pragma unroll
            for (int nt = 0; nt < 8; ++nt) {
                bf16x8 bb = *(const bf16x8*)(bbase + (size_t)nt * 16 * 512 + ks * 32);
                acc[0][nt] = MFMA16(a0, bb, acc[0][nt]);
                acc[1][nt] = MFMA16(a1, bb, acc[1][nt]);
            }
        }
        float rsum[2][4] = {};
#pragma unroll
        for (int nt = 0; nt < 8; ++nt) {
            int col = n0 + nt * 16 + l15;
            float bsv = bsf[col];
#pragma unroll
            for (int mt = 0; mt < 2; ++mt)
#pragma unroll
                for (int reg = 0; reg < 4; ++reg) {
                    int row = t0 + mt * 16 + quad * 4 + reg;
                    float cv = acc[mt][nt][reg] + bsv;
                    rsum[mt][reg] += cv * loadf(Y, ((size_t)bg * T_ + row) * 512 + col, isbf);
                }
        }
#pragma unroll
        for (int mt = 0; mt < 2; ++mt)
#pragma unroll
            for (int reg = 0; reg < 4; ++reg) {
                float r = rsum[mt][reg];
                r += __shfl_xor(r, 1);
                r += __shfl_xor(r, 2);
                r += __shfl_xor(r, 4);
                r += __shfl_xor(r, 8);
                if (l15 == 0) part[wave][mt * 16 + quad * 4 + reg] = r;
            }
    }
    __syncthreads();
    if (threadIdx.x < 32) {
        float v = part[0][threadIdx.x] + part[1][threadIdx.x]
                + part[2][threadIdx.x] + part[3][threadIdx.x];
        logits[bg * 1024 + t0 + threadIdx.x] = v * INV_SCALE;
    }
}

// ---------------- softmax over T + pooled final ----------------
__global__ __launch_bounds__(512) void k_softmax_final(
    const float* __restrict__ logits, const void* __restrict__ Y,
    float* __restrict__ fin, const int* __restrict__ flag)
{
    __shared__ float P[1024];
    __shared__ float red[8];
    __shared__ float sval;
    int isbf = *flag;
    int b = blockIdx.x, tid = threadIdx.x;
    float l0 = logits[b * 1024 + tid];
    float l1 = logits[b * 1024 + 512 + tid];
    float m = fmaxf(l0, l1);
#pragma unroll
    for (int off = 1; off < 64; off <<= 1) m = fmaxf(m, __shfl_xor(m, off));
    if ((tid & 63) == 0) red[tid >> 6] = m;
    __syncthreads();
    if (tid == 0) { float mm = red[0]; for (int i = 1; i < 8; ++i) mm = fmaxf(mm, red[i]); sval = mm; }
    __syncthreads();
    float mx = sval;
    float e0 = __expf(l0 - mx), e1 = __expf(l1 - mx);
    float sacc = e0 + e1;
#pragma unroll
    for (int off = 1; off < 64; off <<= 1) sacc += __shfl_xor(sacc, off);
    if ((tid & 63) == 0) red[tid >> 6] = sacc;
    __syncthreads();
    if (tid == 0) { float ss = 0; for (int i = 0; i < 8; ++i) ss += red[i]; sval = ss; }
    __syncthreads();
    float inv = 1.f / sval;
    P[tid] = e0 * inv;
    P[tid + 512] = e1 * inv;
    __syncthreads();
    float acc = 0.f;
    size_t ybase = (size_t)b * T_ * 512 + tid;
#pragma unroll 4
    for (int t = 0; t < 1024; ++t) acc += P[t] * loadf(Y, ybase + (size_t)t * 512, isbf);
    fin[b * 512 + tid] = acc;
}

// ---------------- out = y_hat + final (broadcast over T) ----------------
__global__ __launch_bounds__(256) void k_output(
    const void* __restrict__ Y, const float* __restrict__ fin,
    void* __restrict__ out, const int* __restrict__ flag)
{
    int isbf = *flag;
    size_t idx = ((size_t)blockIdx.x * 256 + threadIdx.x) * 8;
    int d = (int)(idx & 511);
    int b = (int)(idx >> 19);   // 1024*512 elements per batch
    const float* f = fin + b * 512 + d;
    if (isbf) {
        bf16x8 y = *(const bf16x8*)((const bf16_t*)Y + idx);
        bf16x8 o;
#pragma unroll
        for (int j = 0; j < 8; ++j) o[j] = (bf16_t)((float)y[j] + f[j]);
        *(bf16x8*)((bf16_t*)out + idx) = o;
    } else {
        const floatx4* yp = (const floatx4*)((const float*)Y + idx);
        floatx4 y0 = yp[0], y1 = yp[1], o0, o1;
#pragma unroll
        for (int j = 0; j < 4; ++j) { o0[j] = y0[j] + f[j]; o1[j] = y1[j] + f[j + 4]; }
        floatx4* op = (floatx4*)((float*)out + idx);
        op[0] = o0; op[1] = o1;
    }
}

extern "C" void kernel_launch(void* const* d_in, const int* in_sizes, int n_in,
                              void* d_out, int out_size, void* d_ws, size_t ws_size,
                              hipStream_t stream)
{
    const void* y_hat = d_in[0];
    const void* hist  = d_in[1];
    const void* fore  = d_in[2];
    const void* Wq    = d_in[3];
    const void* bq    = d_in[4];
    const void* Wk    = d_in[5];
    const void* bk    = d_in[6];
    const void* Wv    = d_in[7];
    const void* bv    = d_in[8];
    const void* Ws    = d_in[9];
    const void* bs    = d_in[10];

    // workspace layout — total 51,847,184 B (49.4 MiB), all offsets 16B-aligned
    char* ws = (char*)d_ws;
    int*    flag   = (int*)   (ws);               // 16 B reserved
    float*  bqf    = (float*) (ws + 16);          // 2048 B
    float*  bkf    = (float*) (ws + 2064);
    float*  bvf    = (float*) (ws + 4112);
    float*  bsf    = (float*) (ws + 6160);
    bf16_t* WqT    = (bf16_t*)(ws + 8208);        // 524,288 B
    bf16_t* WsT    = (bf16_t*)(ws + 532496);      // 524,288 B
    bf16_t* WkT    = (bf16_t*)(ws + 1056784);     //  32,768 B
    bf16_t* WvT    = (bf16_t*)(ws + 1089552);     //  32,768 B
    float*  logits = (float*) (ws + 1122320);     // 262,144 B
    float*  finalb = (float*) (ws + 1384464);     // 131,072 B
    bf16_t* Kbuf   = (bf16_t*)(ws + 1515536);     // 25,165,824 B (16 batches)
    bf16_t* VTbuf  = (bf16_t*)(ws + 26681360);    // 25,165,824 B

    k_detect<<<1, 256, 0, stream>>>(y_hat, flag, bq, bk, bv, bs, bqf, bkf, bvf, bsf);
    k_wtrans<<<1024, 256, 0, stream>>>(Wq, Ws, Wk, Wv, WqT, WsT, WkT, WvT, flag);
    for (int p = 0; p < 4; ++p) {
        int b0 = p * BPP;
        k_kvgemm<<<1536, 256, 0, stream>>>(hist, fore, WkT, WvT, bkf, bvf,
                                           Kbuf, VTbuf, flag, b0);
        k_fused<<<512, 256, 0, stream>>>(y_hat, WqT, bqf, Kbuf, VTbuf, WsT, bsf,
                                         logits, flag, b0);
    }
    k_softmax_final<<<64, 512, 0, stream>>>(logits, y_hat, finalb, flag);
    k_output<<<16384, 256, 0, stream>>>(y_hat, finalb, d_out, flag);
}

// Round 2
// 535.986 us; speedup vs baseline: 3.8850x; 3.8850x over previous
//
// MultiFactorAttention MI355X — Round 4: rank-32 algebraic refactor.
//
// Key identity (F=32): scores = y@ (Wk Wq^T)^T @ weather^T, and since
// sum(attn)=1:  logits = (A'·Z)/l + zb  with A' = P@weather [T,32],
// M2 = Wv@Ws, Z = y@M2^T, zb = y·(bv@Ws+bs).  bk cancels in softmax.
// K, V, correction, combined are never materialized. No pass structure.
//
//  k_detect -> flag, bias floats
//  k_wtrans -> WsT bf16
//  k_m12    -> M1 = Wk@Wq^T, M2 = Wv@WsT^T (bf16 [32][512]), b2, bqk
//  k_weather-> Wb [64][1536][32], WbT [64][32][1536] bf16
//  k_qz     -> Q2 (bf16, +bqk), Z (f32), zb (f32)
//  k_attn   -> logits (wave-independent flash in f=32 space)
//  k_finalout-> softmax over T + pooled add, fused output

#include <hip/hip_runtime.h>
#include <hip/hip_bf16.h>

typedef __bf16 bf16_t;
typedef bf16_t bf16x8 __attribute__((ext_vector_type(8)));
typedef bf16_t bf16x4 __attribute__((ext_vector_type(4)));
typedef float  floatx4 __attribute__((ext_vector_type(4)));

#define MFMA16(a,b,c) __builtin_amdgcn_mfma_f32_16x16x32_bf16((a),(b),(c),0,0,0)

constexpr float INV_SCALE = 0.04419417382415922f;  // 1/sqrt(512)

// ---- dual-path load helpers (isbf is wave-uniform) ----
__device__ __forceinline__ bf16x8 load8(const void* p, size_t idx, int isbf) {
    if (isbf) return *(const bf16x8*)((const bf16_t*)p + idx);
    const floatx4* f = (const floatx4*)((const float*)p + idx);
    floatx4 a = f[0], b = f[1];
    bf16x8 r;
    r[0]=(bf16_t)a[0]; r[1]=(bf16_t)a[1]; r[2]=(bf16_t)a[2]; r[3]=(bf16_t)a[3];
    r[4]=(bf16_t)b[0]; r[5]=(bf16_t)b[1]; r[6]=(bf16_t)b[2]; r[7]=(bf16_t)b[3];
    return r;
}
__device__ __forceinline__ float loadf(const void* p, size_t idx, int isbf) {
    return isbf ? (float)((const bf16_t*)p)[idx] : ((const float*)p)[idx];
}

// ---------------- dtype detect + bias normalize ----------------
__global__ __launch_bounds__(256) void k_detect(
    const void* __restrict__ y, int* __restrict__ flag,
    const void* __restrict__ bq, const void* __restrict__ bv,
    const void* __restrict__ bs,
    float* __restrict__ bqf, float* __restrict__ bvf, float* __restrict__ bsf)
{
    __shared__ int cnt[4];
    const unsigned* w = (const unsigned*)y;
    unsigned x = w[threadIdx.x];
    unsigned e = (x >> 7) & 0xFFu;            // bf16-exponent field of LOW half
    bool hit = (e >= 100u && e <= 141u);      // plausible N(0,1) bf16 exponent
    unsigned long long m = __ballot(hit);
    if ((threadIdx.x & 63) == 0) cnt[threadIdx.x >> 6] = __popcll(m);
    __syncthreads();
    int isbf = (cnt[0] + cnt[1] + cnt[2] + cnt[3]) >= 128;
    if (threadIdx.x == 0) *flag = isbf;
    for (int i = threadIdx.x; i < 512; i += 256) {
        bqf[i] = loadf(bq, i, isbf);
        bvf[i] = loadf(bv, i, isbf);
        bsf[i] = loadf(bs, i, isbf);
    }
}

// ---------------- Ws transpose (bf16) ----------------
__global__ __launch_bounds__(256) void k_wtrans(
    const void* __restrict__ Ws, bf16_t* __restrict__ WsT,
    const int* __restrict__ flag)
{
    int isbf = *flag;
    int idx = blockIdx.x * 256 + threadIdx.x;   // 262144 = 512*512
    int k = idx >> 9, n = idx & 511;
    WsT[(size_t)n * 512 + k] = (bf16_t)loadf(Ws, idx, isbf);
}

// ---------------- M1 = Wk@Wq^T, M2 = Wv@Ws (both [32][512]), b2, bqk ----------------
__global__ __launch_bounds__(256) void k_m12(
    const void* __restrict__ Wq, const void* __restrict__ Wk,
    const void* __restrict__ Wv, const bf16_t* __restrict__ WsT,
    const float* __restrict__ bqf, const float* __restrict__ bvf,
    const float* __restrict__ bsf,
    bf16_t* __restrict__ M1, bf16_t* __restrict__ M2,
    float* __restrict__ b2, float* __restrict__ bqk,
    const int* __restrict__ flag)
{
    int isbf = *flag;
    if (blockIdx.x == 0) {
        int wave = threadIdx.x >> 6, lane = threadIdx.x & 63;
        int u = lane & 15, q = lane >> 4;
        int n0 = wave * 128;
        {   // M1[f][d'] = sum_d Wk[f][d] * Wq[d'][d]
            floatx4 acc[2][8] = {};
            for (int ks = 0; ks < 16; ++ks) {
                bf16x8 a0 = load8(Wk, (size_t)u * 512 + ks * 32 + q * 8, isbf);
                bf16x8 a1 = load8(Wk, (size_t)(16 + u) * 512 + ks * 32 + q * 8, isbf);
#pragma unroll
                for (int nt = 0; nt < 8; ++nt) {
                    bf16x8 bb = load8(Wq, (size_t)(n0 + nt * 16 + u) * 512 + ks * 32 + q * 8, isbf);
                    acc[0][nt] = MFMA16(a0, bb, acc[0][nt]);
                    acc[1][nt] = MFMA16(a1, bb, acc[1][nt]);
                }
            }
#pragma unroll
            for (int mt = 0; mt < 2; ++mt)
#pragma unroll
                for (int nt = 0; nt < 8; ++nt)
#pragma unroll
                    for (int r = 0; r < 4; ++r)
                        M1[(size_t)(mt * 16 + q * 4 + r) * 512 + n0 + nt * 16 + u] =
                            (bf16_t)acc[mt][nt][r];
        }
        {   // M2[f][n] = sum_d Wv[f][d] * WsT[n][d]
            floatx4 acc[2][8] = {};
            for (int ks = 0; ks < 16; ++ks) {
                bf16x8 a0 = load8(Wv, (size_t)u * 512 + ks * 32 + q * 8, isbf);
                bf16x8 a1 = load8(Wv, (size_t)(16 + u) * 512 + ks * 32 + q * 8, isbf);
#pragma unroll
                for (int nt = 0; nt < 8; ++nt) {
                    bf16x8 bb = *(const bf16x8*)(WsT + (size_t)(n0 + nt * 16 + u) * 512 + ks * 32 + q * 8);
                    acc[0][nt] = MFMA16(a0, bb, acc[0][nt]);
                    acc[1][nt] = MFMA16(a1, bb, acc[1][nt]);
                }
            }
#pragma unroll
            for (int mt = 0; mt < 2; ++mt)
#pragma unroll
                for (int nt = 0; nt < 8; ++nt)
#pragma unroll
                    for (int r = 0; r < 4; ++r)
                        M2[(size_t)(mt * 16 + q * 4 + r) * 512 + n0 + nt * 16 + u] =
                            (bf16_t)acc[mt][nt][r];
        }
    } else if (blockIdx.x <= 2) {
        int n = (blockIdx.x - 1) * 256 + threadIdx.x;
        float s = 0.f;
        for (int d = 0; d < 512; ++d) s += bvf[d] * (float)WsT[(size_t)n * 512 + d];
        b2[n] = s + bsf[n];
    } else {
        if (threadIdx.x < 32) {
            int f = threadIdx.x;
            float s = 0.f;
            for (int d = 0; d < 512; ++d) s += bqf[d] * loadf(Wk, (size_t)f * 512 + d, isbf);
            bqk[f] = s;
        }
    }
}

// ---------------- weather concat: Wb [b][1536][32], WbT [b][32][1536] ----------------
__global__ __launch_bounds__(256) void k_weather(
    const void* __restrict__ hist, const void* __restrict__ fore,
    bf16_t* __restrict__ Wb, bf16_t* __restrict__ WbT,
    const int* __restrict__ flag)
{
    __shared__ bf16_t tile[32][36];
    int isbf = *flag;
    int b = blockIdx.x / 48, st = blockIdx.x % 48;
    int s0 = st * 32;
    int sl = threadIdx.x >> 3, f0 = (threadIdx.x & 7) * 4;
    int s = s0 + sl;
    const void* sp; size_t src;
    if (s < 1024) { sp = hist; src = ((size_t)b * 1024 + s) * 32 + f0; }
    else          { sp = fore; src = ((size_t)b * 512 + (s - 1024)) * 32 + f0; }
    bf16x4 v;
    if (isbf) v = *(const bf16x4*)((const bf16_t*)sp + src);
    else {
        floatx4 fv = *(const floatx4*)((const float*)sp + src);
#pragma unroll
        for (int i = 0; i < 4; ++i) v[i] = (bf16_t)fv[i];
    }
    *(bf16x4*)(Wb + ((size_t)b * 1536 + s) * 32 + f0) = v;
#pragma unroll
    for (int i = 0; i < 4; ++i) tile[sl][f0 + i] = v[i];
    __syncthreads();
    int f = threadIdx.x >> 3, so = (threadIdx.x & 7) * 4;
    bf16x4 w;
#pragma unroll
    for (int i = 0; i < 4; ++i) w[i] = tile[so + i][f];
    *(bf16x4*)(WbT + ((size_t)b * 32 + f) * 1536 + s0 + so) = w;
}

// ---------------- Q2 = y@M1^T (+bqk), Z = y@M2^T, zb = y·b2 ----------------
__global__ __launch_bounds__(256) void k_qz(
    const void* __restrict__ Y, const bf16_t* __restrict__ M1,
    const bf16_t* __restrict__ M2, const float* __restrict__ bqk,
    const float* __restrict__ b2,
    bf16_t* __restrict__ Q2, float* __restrict__ Z, float* __restrict__ zb,
    const int* __restrict__ flag)
{
    int isbf = *flag;
    int wave = threadIdx.x >> 6, lane = threadIdx.x & 63;
    int u = lane & 15, q = lane >> 4;
    size_t r0 = (size_t)blockIdx.x * 64 + wave * 16;
    floatx4 accQ[2] = {}, accZ[2] = {};
    float zbp = 0.f;
    for (int ks = 0; ks < 16; ++ks) {
        bf16x8 a = load8(Y, (r0 + u) * 512 + ks * 32 + q * 8, isbf);
        const floatx4* bp = (const floatx4*)(b2 + ks * 32 + q * 8);
        floatx4 b2a = bp[0], b2b = bp[1];
#pragma unroll
        for (int j = 0; j < 4; ++j) zbp += (float)a[j] * b2a[j];
#pragma unroll
        for (int j = 0; j < 4; ++j) zbp += (float)a[4 + j] * b2b[j];
#pragma unroll
        for (int nt = 0; nt < 2; ++nt) {
            bf16x8 b1 = *(const bf16x8*)(M1 + (size_t)(nt * 16 + u) * 512 + ks * 32 + q * 8);
            bf16x8 b2v = *(const bf16x8*)(M2 + (size_t)(nt * 16 + u) * 512 + ks * 32 + q * 8);
            accQ[nt] = MFMA16(a, b1, accQ[nt]);
            accZ[nt] = MFMA16(a, b2v, accZ[nt]);
        }
    }
#pragma unroll
    for (int nt = 0; nt < 2; ++nt) {
        float bq_ = bqk[nt * 16 + u];
#pragma unroll
        for (int r = 0; r < 4; ++r) {
            size_t row = r0 + q * 4 + r;
            Q2[row * 32 + nt * 16 + u] = (bf16_t)(accQ[nt][r] + bq_);
            Z [row * 32 + nt * 16 + u] = accZ[nt][r];
        }
    }
    zbp += __shfl_xor(zbp, 16);
    zbp += __shfl_xor(zbp, 32);
    if (q == 0) zb[r0 + u] = zbp;
}

// ---------------- flash attention in f=32 space, wave-independent ----------------
__global__ __launch_bounds__(256) void k_attn(
    const bf16_t* __restrict__ Wb, const bf16_t* __restrict__ WbT,
    const bf16_t* __restrict__ Q2, const float* __restrict__ Z,
    const float* __restrict__ zb, float* __restrict__ logits)
{
    __shared__ bf16_t P_lds[4][2][16][40];   // [wave][dbuf][t][s(+pad)]
    int wave = threadIdx.x >> 6, lane = threadIdx.x & 63;
    int u = lane & 15, q = lane >> 4;
    int b = blockIdx.x >> 4;
    int t0 = (blockIdx.x & 15) * 64 + wave * 16;
    const bf16_t* wbB = Wb  + (size_t)b * 1536 * 32;
    const bf16_t* wtB = WbT + (size_t)b * 32 * 1536;
    // B-frag: Q2[n=t][k=f]
    bf16x8 q2f = *(const bf16x8*)(Q2 + ((size_t)b * 1024 + t0 + u) * 32 + q * 8);
    floatx4 acc[2] = {};                     // A'^T[f=ft*16+q*4+r][t=u]
    float l_acc = 0.f;
    const floatx4 z4 = {};
    for (int c = 0; c < 48; ++c) {
        int sB = c * 32, db = c & 1;
        // A-frags: Wb[s][f] rows
        bf16x8 a0  = *(const bf16x8*)(wbB + (size_t)(sB + u) * 32 + q * 8);
        bf16x8 a1  = *(const bf16x8*)(wbB + (size_t)(sB + 16 + u) * 32 + q * 8);
        // A-frags for A' accumulation: WbT[f][s]
        bf16x8 wt0 = *(const bf16x8*)(wtB + (size_t)u * 1536 + sB + q * 8);
        bf16x8 wt1 = *(const bf16x8*)(wtB + (size_t)(16 + u) * 1536 + sB + q * 8);
        // S^T = mfma(w, Q2): col=t(u), row=s_local(q*4+r)
        floatx4 st0 = MFMA16(a0, q2f, z4);
        floatx4 st1 = MFMA16(a1, q2f, z4);
        bf16x4 p0, p1;
#pragma unroll
        for (int r = 0; r < 4; ++r) {
            float e0 = __expf(st0[r] * INV_SCALE);
            float e1 = __expf(st1[r] * INV_SCALE);
            l_acc += e0 + e1;
            p0[r] = (bf16_t)e0; p1[r] = (bf16_t)e1;
        }
        // wave-private micro-transpose: P^T[s][t] -> B-frag [n=t][k=s]
        *(bf16x4*)&P_lds[wave][db][u][q * 4]      = p0;
        *(bf16x4*)&P_lds[wave][db][u][16 + q * 4] = p1;
        bf16x8 pb = *(const bf16x8*)&P_lds[wave][db][u][q * 8];
        acc[0] = MFMA16(wt0, pb, acc[0]);
        acc[1] = MFMA16(wt1, pb, acc[1]);
    }
    // l rowsum: quad-reduce (t = u fixed per lane)
    float l1 = l_acc + __shfl_xor(l_acc, 16);
    float lf = l1 + __shfl_xor(l1, 32);
    // logits[t] = (A'·Z)/l + zb, scaled
    const float* zp = Z + ((size_t)b * 1024 + t0 + u) * 32 + q * 4;
    floatx4 z0 = *(const floatx4*)zp;
    floatx4 z1 = *(const floatx4*)(zp + 16);
    float dp = 0.f;
#pragma unroll
    for (int r = 0; r < 4; ++r) dp += acc[0][r] * z0[r] + acc[1][r] * z1[r];
    float d1 = dp + __shfl_xor(dp, 16);
    float df = d1 + __shfl_xor(d1, 32);
    if (q == 0)
        logits[(size_t)b * 1024 + t0 + u] =
            (df / lf + zb[(size_t)b * 1024 + t0 + u]) * INV_SCALE;
}

// ---------------- softmax over T + pooled add, fused output ----------------
__global__ __launch_bounds__(256) void k_finalout(
    const float* __restrict__ logits, const void* __restrict__ Y,
    void* __restrict__ out, const int* __restrict__ flag)
{
    __shared__ float P[1024];
    __shared__ float red[4];
    __shared__ float red2[4][64];
    __shared__ float ffin[64];
    __shared__ float s_max, s_sum;
    int isbf = *flag;
    int b = blockIdx.x >> 3, dc = blockIdx.x & 7;
    int tid = threadIdx.x, wid = tid >> 6;
    float l4[4];
#pragma unroll
    for (int i = 0; i < 4; ++i) l4[i] = logits[(size_t)b * 1024 + tid * 4 + i];
    float m = fmaxf(fmaxf(l4[0], l4[1]), fmaxf(l4[2], l4[3]));
#pragma unroll
    for (int off = 1; off < 64; off <<= 1) m = fmaxf(m, __shfl_xor(m, off));
    if ((tid & 63) == 0) red[wid] = m;
    __syncthreads();
    if (tid == 0) s_max = fmaxf(fmaxf(red[0], red[1]), fmaxf(red[2], red[3]));
    __syncthreads();
    float mx = s_max, ls = 0.f;
#pragma unroll
    for (int i = 0; i < 4; ++i) {
        float e = __expf(l4[i] - mx);
        P[tid * 4 + i] = e;
        ls += e;
    }
#pragma unroll
    for (int off = 1; off < 64; off <<= 1) ls += __shfl_xor(ls, off);
    if ((tid & 63) == 0) red[wid] = ls;
    __syncthreads();
    if (tid == 0) s_sum = red[0] + red[1] + red[2] + red[3];
    __syncthreads();
    int d = dc * 64 + (tid & 63), tg = tid >> 6;
    size_t ybase = (size_t)b * 1024 * 512;
    float acc = 0.f;
    for (int t = tg * 256; t < tg * 256 + 256; ++t)
        acc += P[t] * loadf(Y, ybase + (size_t)t * 512 + d, isbf);
    red2[tg][tid & 63] = acc;
    __syncthreads();
    if (tg == 0) ffin[tid] = (red2[0][tid] + red2[1][tid] + red2[2][tid] + red2[3][tid]) / s_sum;
    __syncthreads();
    float fv = ffin[tid & 63];
    if (isbf) {
        bf16_t* o = (bf16_t*)out; const bf16_t* y = (const bf16_t*)Y;
        for (int t = tg * 256; t < tg * 256 + 256; ++t) {
            size_t idx = ybase + (size_t)t * 512 + d;
            o[idx] = (bf16_t)((float)y[idx] + fv);
        }
    } else {
        float* o = (float*)out; const float* y = (const float*)Y;
        for (int t = tg * 256; t < tg * 256 + 256; ++t) {
            size_t idx = ybase + (size_t)t * 512 + d;
            o[idx] = y[idx] + fv;
        }
    }
}

extern "C" void kernel_launch(void* const* d_in, const int* in_sizes, int n_in,
                              void* d_out, int out_size, void* d_ws, size_t ws_size,
                              hipStream_t stream)
{
    const void* y_hat = d_in[0];
    const void* hist  = d_in[1];
    const void* fore  = d_in[2];
    const void* Wq    = d_in[3];
    const void* bq    = d_in[4];
    const void* Wk    = d_in[5];
    // d_in[6] = bk — cancels in softmax, unused
    const void* Wv    = d_in[7];
    const void* bv    = d_in[8];
    const void* Ws    = d_in[9];
    const void* bs    = d_in[10];

    // workspace layout — total 26,288,272 B (~25.1 MiB), 16B-aligned offsets
    char* ws = (char*)d_ws;
    int*    flag   = (int*)   (ws);               // 16
    float*  bqf    = (float*) (ws + 16);          // 2048
    float*  bvf    = (float*) (ws + 2064);        // 2048
    float*  bsf    = (float*) (ws + 4112);        // 2048
    float*  bqk    = (float*) (ws + 6160);        // 128
    float*  b2     = (float*) (ws + 6288);        // 2048
    bf16_t* WsT    = (bf16_t*)(ws + 8336);        // 524288
    bf16_t* M1     = (bf16_t*)(ws + 532624);      // 32768
    bf16_t* M2     = (bf16_t*)(ws + 565392);      // 32768
    bf16_t* Wb     = (bf16_t*)(ws + 598160);      // 6291456
    bf16_t* WbT    = (bf16_t*)(ws + 6889616);     // 6291456
    bf16_t* Q2     = (bf16_t*)(ws + 13181072);    // 4194304
    float*  Z      = (float*) (ws + 17375376);    // 8388608
    float*  zb     = (float*) (ws + 25763984);    // 262144
    float*  logits = (float*) (ws + 26026128);    // 262144

    k_detect  <<<1,    256, 0, stream>>>(y_hat, flag, bq, bv, bs, bqf, bvf, bsf);
    k_wtrans  <<<1024, 256, 0, stream>>>(Ws, WsT, flag);
    k_m12     <<<4,    256, 0, stream>>>(Wq, Wk, Wv, WsT, bqf, bvf, bsf,
                                         M1, M2, b2, bqk, flag);
    k_weather <<<3072, 256, 0, stream>>>(hist, fore, Wb, WbT, flag);
    k_qz      <<<1024, 256, 0, stream>>>(y_hat, M1, M2, bqk, b2, Q2, Z, zb, flag);
    k_attn    <<<1024, 256, 0, stream>>>(Wb, WbT, Q2, Z, zb, logits);
    k_finalout<<<512,  256, 0, stream>>>(logits, y_hat, d_out, flag);
}

// Round 3
// 514.209 us; speedup vs baseline: 4.0495x; 1.0424x over previous
//
// MultiFactorAttention MI355X — Round 5: fix k_m12 latency disaster + pipeline cleanup.
//
// Rank-32 algebra (unchanged, verified passing):
//   scores = y@(Wk Wq^T)^T @ weather^T ; bk cancels in softmax.
//   logits = (A'.Z)/l + zb ; A' = P@weather, M2 = Wv@Ws, Z = y@M2^T, zb = y.(bv@Ws+bs)
//
// Round-5 changes:
//  - per-wave detect_isbf() in every kernel (no flag round-trip, k_detect removed)
//  - k_prep1: LDS-tiled Ws->WsT transpose (coalesced both sides)
//  - k_prep2: M1/M2 MFMA (block 0) + b2/bqk rewritten wave-parallel COALESCED
//    (old k_m12 blocks 1-3 were 130us serial-scalar-chain; predicted <10us)
//  - k_attn: XCD-aware block swizzle (8 batches/XCD -> Wb/WbT L2-resident)
//  - k_finalout split: k_pool (softmax + atomic pooled sums) + k_out (streaming add)

#include <hip/hip_runtime.h>
#include <hip/hip_bf16.h>

typedef __bf16 bf16_t;
typedef bf16_t bf16x8 __attribute__((ext_vector_type(8)));
typedef bf16_t bf16x4 __attribute__((ext_vector_type(4)));
typedef float  floatx4 __attribute__((ext_vector_type(4)));
typedef float  floatx2 __attribute__((ext_vector_type(2)));

#define MFMA16(a,b,c) __builtin_amdgcn_mfma_f32_16x16x32_bf16((a),(b),(c),0,0,0)

constexpr float INV_SCALE = 0.04419417382415922f;  // 1/sqrt(512)

// ---- wave-uniform dtype detect (no cross-kernel flag) ----
__device__ __forceinline__ int detect_isbf(const void* y) {
    unsigned x = ((const unsigned*)y)[threadIdx.x & 63];
    unsigned e = (x >> 7) & 0xFFu;            // bf16 exponent field of LOW half
    unsigned long long m = __ballot(e >= 100u && e <= 141u);
    return __popcll(m) >= 32;                 // bf16: ~64 hits; fp32: ~10
}

// ---- dual-path load helpers (isbf is wave-uniform) ----
__device__ __forceinline__ bf16x8 load8(const void* p, size_t idx, int isbf) {
    if (isbf) return *(const bf16x8*)((const bf16_t*)p + idx);
    const floatx4* f = (const floatx4*)((const float*)p + idx);
    floatx4 a = f[0], b = f[1];
    bf16x8 r;
    r[0]=(bf16_t)a[0]; r[1]=(bf16_t)a[1]; r[2]=(bf16_t)a[2]; r[3]=(bf16_t)a[3];
    r[4]=(bf16_t)b[0]; r[5]=(bf16_t)b[1]; r[6]=(bf16_t)b[2]; r[7]=(bf16_t)b[3];
    return r;
}
__device__ __forceinline__ float loadf(const void* p, size_t idx, int isbf) {
    return isbf ? (float)((const bf16_t*)p)[idx] : ((const float*)p)[idx];
}

// ---------------- Ws -> WsT (bf16), LDS-tiled, coalesced both sides ----------------
__global__ __launch_bounds__(256) void k_prep1(
    const void* __restrict__ Ws, bf16_t* __restrict__ WsT,
    const void* __restrict__ Y)
{
    __shared__ float t[32][33];
    int isbf = detect_isbf(Y);
    int ti = blockIdx.x >> 4, tj = blockIdx.x & 15;
    int r = threadIdx.x >> 3, c0 = (threadIdx.x & 7) * 4;
    size_t base = (size_t)(ti * 32 + r) * 512 + tj * 32 + c0;
#pragma unroll
    for (int i = 0; i < 4; ++i) t[r][c0 + i] = loadf(Ws, base + i, isbf);
    __syncthreads();
    bf16x4 v;
#pragma unroll
    for (int i = 0; i < 4; ++i) v[i] = (bf16_t)t[c0 + i][r];
    *(bf16x4*)(WsT + (size_t)(tj * 32 + r) * 512 + ti * 32 + c0) = v;
}

// ---------------- M1 = Wk@Wq^T, M2 = Wv@Ws (bf16 [32][512]); b2; bqk ----------------
__global__ __launch_bounds__(256) void k_prep2(
    const void* __restrict__ Wq, const void* __restrict__ Wk,
    const void* __restrict__ Wv, const void* __restrict__ Ws,
    const bf16_t* __restrict__ WsT,
    const void* __restrict__ bq, const void* __restrict__ bv,
    const void* __restrict__ bs,
    bf16_t* __restrict__ M1, bf16_t* __restrict__ M2,
    float* __restrict__ b2, float* __restrict__ bqk,
    const void* __restrict__ Y)
{
    int isbf = detect_isbf(Y);
    int tid = threadIdx.x;
    if (blockIdx.x == 0) {
        int wave = tid >> 6, lane = tid & 63;
        int u = lane & 15, q = lane >> 4;
        int n0 = wave * 128;
        {   // M1[f][d'] = sum_d Wk[f][d] * Wq[d'][d]
            floatx4 acc[2][8] = {};
            for (int ks = 0; ks < 16; ++ks) {
                bf16x8 a0 = load8(Wk, (size_t)u * 512 + ks * 32 + q * 8, isbf);
                bf16x8 a1 = load8(Wk, (size_t)(16 + u) * 512 + ks * 32 + q * 8, isbf);
#pragma unroll
                for (int nt = 0; nt < 8; ++nt) {
                    bf16x8 bb = load8(Wq, (size_t)(n0 + nt * 16 + u) * 512 + ks * 32 + q * 8, isbf);
                    acc[0][nt] = MFMA16(a0, bb, acc[0][nt]);
                    acc[1][nt] = MFMA16(a1, bb, acc[1][nt]);
                }
            }
#pragma unroll
            for (int mt = 0; mt < 2; ++mt)
#pragma unroll
                for (int nt = 0; nt < 8; ++nt)
#pragma unroll
                    for (int r = 0; r < 4; ++r)
                        M1[(size_t)(mt * 16 + q * 4 + r) * 512 + n0 + nt * 16 + u] =
                            (bf16_t)acc[mt][nt][r];
        }
        {   // M2[f][n] = sum_d Wv[f][d] * WsT[n][d]
            floatx4 acc[2][8] = {};
            for (int ks = 0; ks < 16; ++ks) {
                bf16x8 a0 = load8(Wv, (size_t)u * 512 + ks * 32 + q * 8, isbf);
                bf16x8 a1 = load8(Wv, (size_t)(16 + u) * 512 + ks * 32 + q * 8, isbf);
#pragma unroll
                for (int nt = 0; nt < 8; ++nt) {
                    bf16x8 bb = *(const bf16x8*)(WsT + (size_t)(n0 + nt * 16 + u) * 512 + ks * 32 + q * 8);
                    acc[0][nt] = MFMA16(a0, bb, acc[0][nt]);
                    acc[1][nt] = MFMA16(a1, bb, acc[1][nt]);
                }
            }
#pragma unroll
            for (int mt = 0; mt < 2; ++mt)
#pragma unroll
                for (int nt = 0; nt < 8; ++nt)
#pragma unroll
                    for (int r = 0; r < 4; ++r)
                        M2[(size_t)(mt * 16 + q * 4 + r) * 512 + n0 + nt * 16 + u] =
                            (bf16_t)acc[mt][nt][r];
        }
    } else if (blockIdx.x <= 2) {
        // b2[n] = sum_d bv[d]*Ws[d][n] + bs[n] — lanes over n (coalesced), serial d
        int n = (blockIdx.x - 1) * 256 + tid;
        float acc = 0.f;
#pragma unroll 4
        for (int d = 0; d < 512; ++d)
            acc += loadf(bv, d, isbf) * loadf(Ws, (size_t)d * 512 + n, isbf);
        b2[n] = acc + loadf(bs, n, isbf);
    } else {
        // bqk[f] = sum_d bq[d]*Wk[f][d] — lanes over d, shuffle reduce
        int wv = tid >> 6, lane = tid & 63;
        int d0 = lane * 8;
#pragma unroll
        for (int i = 0; i < 8; ++i) {
            int f = wv * 8 + i;
            float acc = 0.f;
#pragma unroll
            for (int j = 0; j < 8; ++j)
                acc += loadf(bq, d0 + j, isbf) * loadf(Wk, (size_t)f * 512 + d0 + j, isbf);
#pragma unroll
            for (int off = 1; off < 64; off <<= 1) acc += __shfl_xor(acc, off);
            if (lane == 0) bqk[f] = acc;
        }
    }
}

// ---------------- weather concat: Wb [b][1536][32], WbT [b][32][1536] ----------------
__global__ __launch_bounds__(256) void k_weather(
    const void* __restrict__ hist, const void* __restrict__ fore,
    bf16_t* __restrict__ Wb, bf16_t* __restrict__ WbT,
    const void* __restrict__ Y)
{
    __shared__ bf16_t tile[32][36];
    int isbf = detect_isbf(Y);
    int b = blockIdx.x / 48, st = blockIdx.x % 48;
    int s0 = st * 32;
    int sl = threadIdx.x >> 3, f0 = (threadIdx.x & 7) * 4;
    int s = s0 + sl;
    const void* sp; size_t src;
    if (s < 1024) { sp = hist; src = ((size_t)b * 1024 + s) * 32 + f0; }
    else          { sp = fore; src = ((size_t)b * 512 + (s - 1024)) * 32 + f0; }
    bf16x4 v;
    if (isbf) v = *(const bf16x4*)((const bf16_t*)sp + src);
    else {
        floatx4 fv = *(const floatx4*)((const float*)sp + src);
#pragma unroll
        for (int i = 0; i < 4; ++i) v[i] = (bf16_t)fv[i];
    }
    *(bf16x4*)(Wb + ((size_t)b * 1536 + s) * 32 + f0) = v;
#pragma unroll
    for (int i = 0; i < 4; ++i) tile[sl][f0 + i] = v[i];
    __syncthreads();
    int f = threadIdx.x >> 3, so = (threadIdx.x & 7) * 4;
    bf16x4 w;
#pragma unroll
    for (int i = 0; i < 4; ++i) w[i] = tile[so + i][f];
    *(bf16x4*)(WbT + ((size_t)b * 32 + f) * 1536 + s0 + so) = w;
}

// ---------------- Q2 = y@M1^T (+bqk), Z = y@M2^T, zb = y·b2 ----------------
__global__ __launch_bounds__(256) void k_qz(
    const void* __restrict__ Y, const bf16_t* __restrict__ M1,
    const bf16_t* __restrict__ M2, const float* __restrict__ bqk,
    const float* __restrict__ b2,
    bf16_t* __restrict__ Q2, float* __restrict__ Z, float* __restrict__ zb)
{
    int isbf = detect_isbf(Y);
    int wave = threadIdx.x >> 6, lane = threadIdx.x & 63;
    int u = lane & 15, q = lane >> 4;
    size_t r0 = (size_t)blockIdx.x * 64 + wave * 16;
    floatx4 accQ[2] = {}, accZ[2] = {};
    float zbp = 0.f;
    for (int ks = 0; ks < 16; ++ks) {
        bf16x8 a = load8(Y, (r0 + u) * 512 + ks * 32 + q * 8, isbf);
        const floatx4* bp = (const floatx4*)(b2 + ks * 32 + q * 8);
        floatx4 b2a = bp[0], b2b = bp[1];
#pragma unroll
        for (int j = 0; j < 4; ++j) zbp += (float)a[j] * b2a[j];
#pragma unroll
        for (int j = 0; j < 4; ++j) zbp += (float)a[4 + j] * b2b[j];
#pragma unroll
        for (int nt = 0; nt < 2; ++nt) {
            bf16x8 b1 = *(const bf16x8*)(M1 + (size_t)(nt * 16 + u) * 512 + ks * 32 + q * 8);
            bf16x8 b2v = *(const bf16x8*)(M2 + (size_t)(nt * 16 + u) * 512 + ks * 32 + q * 8);
            accQ[nt] = MFMA16(a, b1, accQ[nt]);
            accZ[nt] = MFMA16(a, b2v, accZ[nt]);
        }
    }
#pragma unroll
    for (int nt = 0; nt < 2; ++nt) {
        float bq_ = bqk[nt * 16 + u];
#pragma unroll
        for (int r = 0; r < 4; ++r) {
            size_t row = r0 + q * 4 + r;
            Q2[row * 32 + nt * 16 + u] = (bf16_t)(accQ[nt][r] + bq_);
            Z [row * 32 + nt * 16 + u] = accZ[nt][r];
        }
    }
    zbp += __shfl_xor(zbp, 16);
    zbp += __shfl_xor(zbp, 32);
    if (q == 0) zb[r0 + u] = zbp;
}

// ---------------- flash attention in f=32 space, wave-independent ----------------
__global__ __launch_bounds__(256) void k_attn(
    const bf16_t* __restrict__ Wb, const bf16_t* __restrict__ WbT,
    const bf16_t* __restrict__ Q2, const float* __restrict__ Z,
    const float* __restrict__ zb, float* __restrict__ logits)
{
    __shared__ bf16_t P_lds[4][2][16][40];   // [wave][dbuf][t][s(+pad)]
    int wave = threadIdx.x >> 6, lane = threadIdx.x & 63;
    int u = lane & 15, q = lane >> 4;
    // XCD-aware swizzle: 1024 blocks, 8 XCDs -> each XCD owns 8 consecutive batches
    int swz = ((blockIdx.x & 7) << 7) | (blockIdx.x >> 3);
    int b = swz >> 4;
    int t0 = (swz & 15) * 64 + wave * 16;
    const bf16_t* wbB = Wb  + (size_t)b * 1536 * 32;
    const bf16_t* wtB = WbT + (size_t)b * 32 * 1536;
    // B-frag: Q2[n=t][k=f]
    bf16x8 q2f = *(const bf16x8*)(Q2 + ((size_t)b * 1024 + t0 + u) * 32 + q * 8);
    floatx4 acc[2] = {};                     // A'^T[f=ft*16+q*4+r][t=u]
    float l_acc = 0.f;
    const floatx4 z4 = {};
    for (int c = 0; c < 48; ++c) {
        int sB = c * 32, db = c & 1;
        bf16x8 a0  = *(const bf16x8*)(wbB + (size_t)(sB + u) * 32 + q * 8);
        bf16x8 a1  = *(const bf16x8*)(wbB + (size_t)(sB + 16 + u) * 32 + q * 8);
        bf16x8 wt0 = *(const bf16x8*)(wtB + (size_t)u * 1536 + sB + q * 8);
        bf16x8 wt1 = *(const bf16x8*)(wtB + (size_t)(16 + u) * 1536 + sB + q * 8);
        floatx4 st0 = MFMA16(a0, q2f, z4);   // S^T: col=t(u), row=s_local
        floatx4 st1 = MFMA16(a1, q2f, z4);
        bf16x4 p0, p1;
#pragma unroll
        for (int r = 0; r < 4; ++r) {
            float e0 = __expf(st0[r] * INV_SCALE);
            float e1 = __expf(st1[r] * INV_SCALE);
            l_acc += e0 + e1;
            p0[r] = (bf16_t)e0; p1[r] = (bf16_t)e1;
        }
        // wave-private micro-transpose: P^T[s][t] -> B-frag [n=t][k=s]
        *(bf16x4*)&P_lds[wave][db][u][q * 4]      = p0;
        *(bf16x4*)&P_lds[wave][db][u][16 + q * 4] = p1;
        bf16x8 pb = *(const bf16x8*)&P_lds[wave][db][u][q * 8];
        acc[0] = MFMA16(wt0, pb, acc[0]);
        acc[1] = MFMA16(wt1, pb, acc[1]);
    }
    float l1 = l_acc + __shfl_xor(l_acc, 16);
    float lf = l1 + __shfl_xor(l1, 32);
    const float* zp = Z + ((size_t)b * 1024 + t0 + u) * 32 + q * 4;
    floatx4 z0 = *(const floatx4*)zp;
    floatx4 z1 = *(const floatx4*)(zp + 16);
    float dp = 0.f;
#pragma unroll
    for (int r = 0; r < 4; ++r) dp += acc[0][r] * z0[r] + acc[1][r] * z1[r];
    float d1 = dp + __shfl_xor(dp, 16);
    float df = d1 + __shfl_xor(d1, 32);
    if (q == 0)
        logits[(size_t)b * 1024 + t0 + u] =
            (df / lf + zb[(size_t)b * 1024 + t0 + u]) * INV_SCALE;
}

// ---------------- softmax over T + pooled partial sums (atomic) ----------------
__global__ __launch_bounds__(256) void k_pool(
    const float* __restrict__ logits, const void* __restrict__ Y,
    float* __restrict__ fin)
{
    __shared__ float P[1024];
    __shared__ float red[4];
    __shared__ float s_val;
    int isbf = detect_isbf(Y);
    int b = blockIdx.x >> 4, ts = blockIdx.x & 15;
    int tid = threadIdx.x, wv = tid >> 6;
    floatx4 l4 = *(const floatx4*)(logits + (size_t)b * 1024 + tid * 4);
    float m = fmaxf(fmaxf(l4[0], l4[1]), fmaxf(l4[2], l4[3]));
#pragma unroll
    for (int off = 1; off < 64; off <<= 1) m = fmaxf(m, __shfl_xor(m, off));
    if ((tid & 63) == 0) red[wv] = m;
    __syncthreads();
    if (tid == 0) s_val = fmaxf(fmaxf(red[0], red[1]), fmaxf(red[2], red[3]));
    __syncthreads();
    float mx = s_val, ls = 0.f;
    floatx4 e;
#pragma unroll
    for (int i = 0; i < 4; ++i) { e[i] = __expf(l4[i] - mx); ls += e[i]; }
    *(floatx4*)&P[tid * 4] = e;
#pragma unroll
    for (int off = 1; off < 64; off <<= 1) ls += __shfl_xor(ls, off);
    __syncthreads();                       // P fully written; red reads done
    if ((tid & 63) == 0) red[wv] = ls;
    __syncthreads();
    if (tid == 0) s_val = red[0] + red[1] + red[2] + red[3];
    __syncthreads();
    float inv = 1.f / s_val;
    int d = tid * 2;
    size_t base = (size_t)b * 1024 * 512 + d;
    float a0 = 0.f, a1 = 0.f;
    int t0 = ts * 64;
#pragma unroll 4
    for (int t = t0; t < t0 + 64; ++t) {
        float y0, y1;
        size_t off = base + (size_t)t * 512;
        if (isbf) {
            y0 = (float)((const bf16_t*)Y)[off];
            y1 = (float)((const bf16_t*)Y)[off + 1];
        } else {
            floatx2 v = *(const floatx2*)((const float*)Y + off);
            y0 = v[0]; y1 = v[1];
        }
        float p = P[t];
        a0 += p * y0; a1 += p * y1;
    }
    atomicAdd(&fin[b * 512 + d], a0 * inv);
    atomicAdd(&fin[b * 512 + d + 1], a1 * inv);
}

// ---------------- out = y_hat + final (broadcast over T) ----------------
__global__ __launch_bounds__(256) void k_out(
    const void* __restrict__ Y, const float* __restrict__ fin,
    void* __restrict__ out)
{
    int isbf = detect_isbf(Y);
    size_t idx = ((size_t)blockIdx.x * 256 + threadIdx.x) * 8;
    int d = (int)(idx & 511);
    int b = (int)(idx >> 19);   // 1024*512 elements per batch
    const float* f = fin + b * 512 + d;
    if (isbf) {
        bf16x8 y = *(const bf16x8*)((const bf16_t*)Y + idx);
        bf16x8 o;
#pragma unroll
        for (int j = 0; j < 8; ++j) o[j] = (bf16_t)((float)y[j] + f[j]);
        *(bf16x8*)((bf16_t*)out + idx) = o;
    } else {
        const floatx4* yp = (const floatx4*)((const float*)Y + idx);
        floatx4 y0 = yp[0], y1 = yp[1], o0, o1;
#pragma unroll
        for (int j = 0; j < 4; ++j) { o0[j] = y0[j] + f[j]; o1[j] = y1[j] + f[j + 4]; }
        floatx4* op = (floatx4*)((float*)out + idx);
        op[0] = o0; op[1] = o1;
    }
}

extern "C" void kernel_launch(void* const* d_in, const int* in_sizes, int n_in,
                              void* d_out, int out_size, void* d_ws, size_t ws_size,
                              hipStream_t stream)
{
    const void* y_hat = d_in[0];
    const void* hist  = d_in[1];
    const void* fore  = d_in[2];
    const void* Wq    = d_in[3];
    const void* bq    = d_in[4];
    const void* Wk    = d_in[5];
    // d_in[6] = bk — cancels in softmax, unused
    const void* Wv    = d_in[7];
    const void* bv    = d_in[8];
    const void* Ws    = d_in[9];
    const void* bs    = d_in[10];

    // workspace layout — total ~25.2 MiB, 128B-aligned offsets
    char* ws = (char*)d_ws;
    bf16_t* WsT    = (bf16_t*)(ws);               // 524288
    bf16_t* M1     = (bf16_t*)(ws + 524288);      // 32768
    bf16_t* M2     = (bf16_t*)(ws + 557056);      // 32768
    float*  bqk    = (float*) (ws + 589824);      // 128
    float*  b2     = (float*) (ws + 589952);      // 2048
    bf16_t* Wb     = (bf16_t*)(ws + 592000);      // 6291456
    bf16_t* WbT    = (bf16_t*)(ws + 6883456);     // 6291456
    bf16_t* Q2     = (bf16_t*)(ws + 13174912);    // 4194304
    float*  Z      = (float*) (ws + 17369216);    // 8388608
    float*  zb     = (float*) (ws + 25757824);    // 262144
    float*  logits = (float*) (ws + 26019968);    // 262144
    float*  fin    = (float*) (ws + 26282112);    // 131072

    k_prep1  <<<256,  256, 0, stream>>>(Ws, WsT, y_hat);
    k_prep2  <<<4,    256, 0, stream>>>(Wq, Wk, Wv, Ws, WsT, bq, bv, bs,
                                        M1, M2, b2, bqk, y_hat);
    k_weather<<<3072, 256, 0, stream>>>(hist, fore, Wb, WbT, y_hat);
    k_qz     <<<1024, 256, 0, stream>>>(y_hat, M1, M2, bqk, b2, Q2, Z, zb);
    k_attn   <<<1024, 256, 0, stream>>>(Wb, WbT, Q2, Z, zb, logits);
    hipMemsetAsync(fin, 0, 64 * 512 * sizeof(float), stream);
    k_pool   <<<1024, 256, 0, stream>>>(logits, y_hat, fin);
    k_out    <<<16384, 256, 0, stream>>>(y_hat, fin, d_out);
}